// Round 6
// baseline (202.527 us; speedup 1.0000x reference)
//
#include <hip/hip_runtime.h>
#include <hip/hip_bf16.h>

#define B_ 16
#define N_ 1024
#define H_ 256
#define HEADS_ 8
#define DH_ 32
#define BN_ (B_*N_)
#define F_ (2*H_)      // 512
#define QKV_ 768

typedef __attribute__((ext_vector_type(8))) __bf16 bf16x8;
typedef __attribute__((ext_vector_type(4))) float floatx4;

// scale(1/sqrt(32)) * log2(e): folded into q so softmax is a bare v_exp (2^x)
#define QSC 0.25506910542339896f

#if __has_builtin(__builtin_amdgcn_exp2f)
#define EXP2(x) __builtin_amdgcn_exp2f(x)
#else
#define EXP2(x) exp2f(x)
#endif

__device__ __forceinline__ unsigned short f2bf(float f) {
    union { float f; unsigned int u; } c; c.f = f;
    unsigned int u = c.u;
    return (unsigned short)((u + 0x7fffu + ((u >> 16) & 1u)) >> 16);
}
__device__ __forceinline__ float bf2f(unsigned short s) {
    union { unsigned int u; float f; } c; c.u = ((unsigned int)s) << 16;
    return c.f;
}
__device__ __forceinline__ unsigned int fbits(float f) {
    union { float f; unsigned int u; } c; c.f = f; return c.u;
}
// pack two floats to bf16x2 via v_perm (round-half-away)
__device__ __forceinline__ unsigned int pk2(float lo, float hi) {
    return __builtin_amdgcn_perm(fbits(hi) + 0x8000u, fbits(lo) + 0x8000u, 0x07060302u);
}

// async global->LDS, 16B per lane; lds dest = wave-uniform base + lane*16
__device__ __forceinline__ void async16(const void* g, void* l) {
    __builtin_amdgcn_global_load_lds(
        (const __attribute__((address_space(1))) unsigned int*)g,
        (__attribute__((address_space(3))) unsigned int*)l,
        16, 0, 0);
}

// ---------------- kernel 1: fused prep = dual LayerNorm + weight pack -----
// blocks [0,4096): LN, 4 rows/block (1 row/wave). blocks [4096,5632): pack.
__global__ __launch_bounds__(256) void prep(
        const float* __restrict__ xs_g, const float* __restrict__ xo_g,
        const float* __restrict__ gs, const float* __restrict__ bs,
        const float* __restrict__ go, const float* __restrict__ bo,
        const float* __restrict__ Wq, const float* __restrict__ Wk,
        const float* __restrict__ Wv, const float* __restrict__ Wo,
        const float* __restrict__ Wp,
        unsigned short* __restrict__ f,
        unsigned short* __restrict__ WcT, unsigned short* __restrict__ WoT,
        float* __restrict__ WoP) {
    if (blockIdx.x < 4096) {
        int t = threadIdx.x & 63;
        int row = blockIdx.x * 4 + (threadIdx.x >> 6);
        const float4 vs = ((const float4*)(xs_g + (size_t)row * H_))[t];
        const float4 vo = ((const float4*)(xo_g + (size_t)row * H_))[t];
        float s1 = vs.x + vs.y + vs.z + vs.w;
        float s2 = vs.x*vs.x + vs.y*vs.y + vs.z*vs.z + vs.w*vs.w;
        float o1 = vo.x + vo.y + vo.z + vo.w;
        float o2 = vo.x*vo.x + vo.y*vo.y + vo.z*vo.z + vo.w*vo.w;
        #pragma unroll
        for (int m = 1; m < 64; m <<= 1) {
            s1 += __shfl_xor(s1, m); s2 += __shfl_xor(s2, m);
            o1 += __shfl_xor(o1, m); o2 += __shfl_xor(o2, m);
        }
        const float inv = 1.0f / 256.0f;
        float ms = s1 * inv, vvs = s2 * inv - ms * ms;
        float mo = o1 * inv, vvo = o2 * inv - mo * mo;
        float rs = rsqrtf(vvs + 1e-5f);
        float ro = rsqrtf(vvo + 1e-5f);
        float4 g4s = ((const float4*)gs)[t];
        float4 b4s = ((const float4*)bs)[t];
        float4 g4o = ((const float4*)go)[t];
        float4 b4o = ((const float4*)bo)[t];
        ushort4 os, oo;
        os.x = f2bf((vs.x - ms) * rs * g4s.x + b4s.x);
        os.y = f2bf((vs.y - ms) * rs * g4s.y + b4s.y);
        os.z = f2bf((vs.z - ms) * rs * g4s.z + b4s.z);
        os.w = f2bf((vs.w - ms) * rs * g4s.w + b4s.w);
        oo.x = f2bf((vo.x - mo) * ro * g4o.x + b4o.x);
        oo.y = f2bf((vo.y - mo) * ro * g4o.y + b4o.y);
        oo.z = f2bf((vo.z - mo) * ro * g4o.z + b4o.z);
        oo.w = f2bf((vo.w - mo) * ro * g4o.w + b4o.w);
        *(ushort4*)(f + (size_t)row * F_ + 4 * t) = os;
        *(ushort4*)(f + (size_t)row * F_ + H_ + 4 * t) = oo;
    } else {
        int i = (blockIdx.x - 4096) * 256 + threadIdx.x;
        const int total1 = QKV_ * F_;   // WcT[n][k]
        if (i < total1) {
            int n = i / F_, k = i % F_;
            float w;
            if (n < 256)      w = Wq[(size_t)k * H_ + n];
            else if (n < 512) w = Wk[(size_t)k * H_ + (n - 256)];
            else              w = Wv[(size_t)k * H_ + (n - 512)];
            WcT[i] = f2bf(w);
        }
        const int total2 = H_ * H_;     // WoT[n][k]
        if (i < total2) {
            int n = i / H_, k = i % H_;
            WoT[i] = f2bf(Wo[(size_t)k * H_ + n]);
        }
        if (i < H_ * 3) {               // WoP = Wo @ Wp folded
            int c = i / 3, j = i % 3;
            float s = 0.f;
            for (int n = 0; n < H_; ++n) s += Wo[(size_t)c * H_ + n] * Wp[n * 3 + j];
            WoP[i] = s;
        }
    }
}

// ---------------- kernel 2: QKV GEMM (128x128 LDS tile) -------------------
// q-section accumulators are prescaled by QSC so attn's softmax is 2^s.
__global__ __launch_bounds__(256) void qkv_gemm(
        const unsigned short* __restrict__ f,
        const unsigned short* __restrict__ WcT,
        unsigned short* __restrict__ qb,
        unsigned short* __restrict__ kb,
        unsigned short* __restrict__ vT) {
    __shared__ __align__(16) unsigned short As[128 * 32];
    __shared__ __align__(16) unsigned short Bs[128 * 32];
    int t = threadIdx.x;
    int w = t >> 6, lane = t & 63;
    int r = lane & 15, qd = lane >> 4;
    int wm = (w >> 1) * 64, wn = (w & 1) * 64;
    int m0 = blockIdx.y * 128, n0 = blockIdx.x * 128;
    int lrow = lane >> 2, lcol = (lane & 3) * 8;
    floatx4 acc[4][4] = {};
    const unsigned short* gA = f   + (size_t)(m0 + w * 32 + lrow) * F_ + lcol;
    const unsigned short* gB = WcT + (size_t)(n0 + w * 32 + lrow) * F_ + lcol;
    unsigned short* lA = As + (w * 32) * 32;
    unsigned short* lB = Bs + (w * 32) * 32;
    for (int k0 = 0; k0 < F_; k0 += 32) {
        async16(gA + k0,            lA);
        async16(gA + k0 + 16 * F_,  lA + 16 * 32);
        async16(gB + k0,            lB);
        async16(gB + k0 + 16 * F_,  lB + 16 * 32);
        __syncthreads();
        bf16x8 aF[4], bF[4];
        #pragma unroll
        for (int mt = 0; mt < 4; ++mt)
            aF[mt] = *(const bf16x8*)(As + (wm + mt * 16 + r) * 32 + qd * 8);
        #pragma unroll
        for (int nt = 0; nt < 4; ++nt)
            bF[nt] = *(const bf16x8*)(Bs + (wn + nt * 16 + r) * 32 + qd * 8);
        #pragma unroll
        for (int mt = 0; mt < 4; ++mt)
            #pragma unroll
            for (int nt = 0; nt < 4; ++nt)
                acc[mt][nt] = __builtin_amdgcn_mfma_f32_16x16x32_bf16(aF[mt], bF[nt], acc[mt][nt], 0, 0, 0);
        __syncthreads();
    }
    #pragma unroll
    for (int nt = 0; nt < 4; ++nt) {
        int cg = n0 + wn + nt * 16 + r;
        int sec = cg >> 8;              // 0=q 1=k 2=v
        int hh = (cg >> 5) & 7;
        int d = cg & 31;
        #pragma unroll
        for (int mt = 0; mt < 4; ++mt) {
            int tok = m0 + wm + mt * 16 + qd * 4;
            int b = tok >> 10, tl = tok & 1023;
            size_t hb = (size_t)b * 8 + hh;
            if (sec == 0) {
                unsigned short* p = qb + (hb * 1024 + tl) * 32 + d;
                #pragma unroll
                for (int i = 0; i < 4; ++i) p[i * 32] = f2bf(acc[mt][nt][i] * QSC);
            } else if (sec == 1) {
                unsigned short* p = kb + (hb * 1024 + tl) * 32 + d;
                #pragma unroll
                for (int i = 0; i < 4; ++i) p[i * 32] = f2bf(acc[mt][nt][i]);
            } else {
                ushort4 v4;
                v4.x = f2bf(acc[mt][nt][0]); v4.y = f2bf(acc[mt][nt][1]);
                v4.z = f2bf(acc[mt][nt][2]); v4.w = f2bf(acc[mt][nt][3]);
                *(ushort4*)(vT + (hb * 32 + d) * 1024 + tl) = v4;
            }
        }
    }
}

// ---------------- kernel 3: flash attention, split-K across waves ---------
// Block = 64 q-rows x one (b,h). Wave w handles keys [w*256,(w+1)*256) for
// ALL 64 q-rows. Partials combined through LDS as packed bf16 pairs (d-major)
// to keep LDS ~18 KB -> 8 blocks/CU residency.
__global__ __launch_bounds__(256) void attn(
        const unsigned short* __restrict__ qb,
        const unsigned short* __restrict__ kb,
        const unsigned short* __restrict__ vT,
        unsigned short* __restrict__ msg) {
    __shared__ unsigned int obu[4][16][66];  // [wave][d2=d>>1][q] bf16x2 pairs
    __shared__ float lb[4][64];              // [wave][q] row-sum partials
    int blk = blockIdx.x;
    int qt = blk & 15;
    int h  = (blk >> 4) & 7;
    int b  = blk >> 7;
    int t = threadIdx.x;
    int w = t >> 6, lane = t & 63;
    int r = lane & 15, qd = lane >> 4;
    int q0 = qt * 64;
    size_t hb = (size_t)b * 8 + h;
    const unsigned short* qs = qb + hb * (1024 * 32);
    const unsigned short* ks = kb + hb * (1024 * 32);
    const unsigned short* vs = vT + hb * (32 * 1024);
    bf16x8 qf[4];
    #pragma unroll
    for (int i = 0; i < 4; ++i)
        qf[i] = *(const bf16x8*)(qs + (size_t)(q0 + i * 16 + r) * 32 + qd * 8);
    union { unsigned int u[4]; bf16x8 v; } onesu;
    onesu.u[0] = onesu.u[1] = onesu.u[2] = onesu.u[3] = 0x3F803F80u;
    const bf16x8 onesv = onesu.v;
    floatx4 o0[4] = {}, o1[4] = {}, ol[4] = {};
    int srcA = ((qd & 1) * 2) * 16 + r;
    int srcB = srcA + 16;
    bool hiq = qd >= 2;
    int kb0 = w * 256;
    for (int kc = 0; kc < 256; kc += 32) {
        int kk = kb0 + kc;
        bf16x8 kf0 = *(const bf16x8*)(ks + (size_t)(kk + r) * 32 + qd * 8);
        bf16x8 kf1 = *(const bf16x8*)(ks + (size_t)(kk + 16 + r) * 32 + qd * 8);
        bf16x8 vf0 = *(const bf16x8*)(vs + (size_t)r * 1024 + kk + qd * 8);
        bf16x8 vf1 = *(const bf16x8*)(vs + (size_t)(16 + r) * 1024 + kk + qd * 8);
        #pragma unroll
        for (int i = 0; i < 4; ++i) {
            floatx4 z = {0.f,0.f,0.f,0.f};
            floatx4 s0 = __builtin_amdgcn_mfma_f32_16x16x32_bf16(kf0, qf[i], z, 0, 0, 0);
            floatx4 s1 = __builtin_amdgcn_mfma_f32_16x16x32_bf16(kf1, qf[i], z, 0, 0, 0);
            float e0[4], e1[4];
            #pragma unroll
            for (int j = 0; j < 4; ++j) {
                e0[j] = EXP2(s0[j]);
                e1[j] = EXP2(s1[j]);
            }
            unsigned int t00 = pk2(e0[0], e0[1]), t01 = pk2(e0[2], e0[3]);
            unsigned int t10 = pk2(e1[0], e1[1]), t11 = pk2(e1[2], e1[3]);
            unsigned int a0 = __shfl((int)t00, srcA), a1 = __shfl((int)t01, srcA);
            unsigned int b0 = __shfl((int)t00, srcB), b1 = __shfl((int)t01, srcB);
            unsigned int c0 = __shfl((int)t10, srcA), c1 = __shfl((int)t11, srcA);
            unsigned int d0 = __shfl((int)t10, srcB), d1 = __shfl((int)t11, srcB);
            union { unsigned int u[4]; bf16x8 v; } pf;
            pf.u[0] = hiq ? c0 : a0;
            pf.u[1] = hiq ? c1 : a1;
            pf.u[2] = hiq ? d0 : b0;
            pf.u[3] = hiq ? d1 : b1;
            o0[i] = __builtin_amdgcn_mfma_f32_16x16x32_bf16(vf0, pf.v, o0[i], 0, 0, 0);
            o1[i] = __builtin_amdgcn_mfma_f32_16x16x32_bf16(vf1, pf.v, o1[i], 0, 0, 0);
            ol[i] = __builtin_amdgcn_mfma_f32_16x16x32_bf16(onesv, pf.v, ol[i], 0, 0, 0);
        }
    }
    // epilogue: pack per-wave partials bf16x2 along d (d2 = d>>1)
    #pragma unroll
    for (int i = 0; i < 4; ++i) {
        obu[w][qd * 2 + 0][i * 16 + r] = pk2(o0[i][0], o0[i][1]);
        obu[w][qd * 2 + 1][i * 16 + r] = pk2(o0[i][2], o0[i][3]);
        obu[w][8 + qd * 2 + 0][i * 16 + r] = pk2(o1[i][0], o1[i][1]);
        obu[w][8 + qd * 2 + 1][i * 16 + r] = pk2(o1[i][2], o1[i][3]);
        if (qd == 0) lb[w][i * 16 + r] = ol[i][0];
    }
    __syncthreads();
    // final: thread (q2 = t>>2, dg = t&3) reduces d = dg*8..dg*8+7 of row q2
    {
        int q2 = t >> 2, dg = t & 3;
        float acc8[8] = {0.f,0.f,0.f,0.f,0.f,0.f,0.f,0.f};
        float L = 0.f;
        #pragma unroll
        for (int ww = 0; ww < 4; ++ww) {
            L += lb[ww][q2];
            #pragma unroll
            for (int jj = 0; jj < 4; ++jj) {
                unsigned int u = obu[ww][dg * 4 + jj][q2];
                union { unsigned int u; float f; } lo, hi;
                lo.u = u << 16; hi.u = u & 0xffff0000u;
                acc8[jj * 2]     += lo.f;
                acc8[jj * 2 + 1] += hi.f;
            }
        }
        float rinv = 1.0f / L;
        uint4 pkd;
        pkd.x = pk2(acc8[0] * rinv, acc8[1] * rinv);
        pkd.y = pk2(acc8[2] * rinv, acc8[3] * rinv);
        pkd.z = pk2(acc8[4] * rinv, acc8[5] * rinv);
        pkd.w = pk2(acc8[6] * rinv, acc8[7] * rinv);
        *(uint4*)(msg + ((size_t)(b * N_ + q0 + q2)) * H_ + h * DH_ + dg * 8) = pkd;
    }
}

// ---------------- kernel 4: Wo GEMM + residual (128x128 LDS tile) ---------
__global__ __launch_bounds__(256) void out_gemm(
        const unsigned short* __restrict__ msg,
        const unsigned short* __restrict__ WoT,
        const float* __restrict__ x_out,
        float* __restrict__ outx) {
    __shared__ __align__(16) unsigned short As[128 * 32];
    __shared__ __align__(16) unsigned short Bs[128 * 32];
    int t = threadIdx.x;
    int w = t >> 6, lane = t & 63;
    int r = lane & 15, qd = lane >> 4;
    int wm = (w >> 1) * 64, wn = (w & 1) * 64;
    int m0 = blockIdx.y * 128, n0 = blockIdx.x * 128;
    int lrow = lane >> 2, lcol = (lane & 3) * 8;
    floatx4 acc[4][4] = {};
    const unsigned short* gA = msg + (size_t)(m0 + w * 32 + lrow) * H_ + lcol;
    const unsigned short* gB = WoT + (size_t)(n0 + w * 32 + lrow) * H_ + lcol;
    unsigned short* lA = As + (w * 32) * 32;
    unsigned short* lB = Bs + (w * 32) * 32;
    for (int k0 = 0; k0 < H_; k0 += 32) {
        async16(gA + k0,           lA);
        async16(gA + k0 + 16 * H_, lA + 16 * 32);
        async16(gB + k0,           lB);
        async16(gB + k0 + 16 * H_, lB + 16 * 32);
        __syncthreads();
        bf16x8 aF[4], bF[4];
        #pragma unroll
        for (int mt = 0; mt < 4; ++mt)
            aF[mt] = *(const bf16x8*)(As + (wm + mt * 16 + r) * 32 + qd * 8);
        #pragma unroll
        for (int nt = 0; nt < 4; ++nt)
            bF[nt] = *(const bf16x8*)(Bs + (wn + nt * 16 + r) * 32 + qd * 8);
        #pragma unroll
        for (int mt = 0; mt < 4; ++mt)
            #pragma unroll
            for (int nt = 0; nt < 4; ++nt)
                acc[mt][nt] = __builtin_amdgcn_mfma_f32_16x16x32_bf16(aF[mt], bF[nt], acc[mt][nt], 0, 0, 0);
        __syncthreads();
    }
    #pragma unroll
    for (int nt = 0; nt < 4; ++nt) {
        int cg = n0 + wn + nt * 16 + r;
        #pragma unroll
        for (int mt = 0; mt < 4; ++mt) {
            int tok = m0 + wm + mt * 16 + qd * 4;
            #pragma unroll
            for (int i = 0; i < 4; ++i) {
                size_t idx = (size_t)(tok + i) * H_ + cg;
                outx[idx] = x_out[idx] + acc[mt][nt][i];
            }
        }
    }
}

// ---------------- kernel 5: position head  p = msg @ WoP ------------------
__global__ __launch_bounds__(64) void p_kernel(
        const unsigned short* __restrict__ msg, const float* __restrict__ WoP,
        float* __restrict__ outp) {
    int row = blockIdx.x;
    int t = threadIdx.x;
    float a0 = 0.f, a1 = 0.f, a2 = 0.f;
    #pragma unroll
    for (int i = 0; i < 4; ++i) {
        int c = t + 64 * i;
        float v = bf2f(msg[(size_t)row * H_ + c]);
        a0 += v * WoP[c * 3 + 0];
        a1 += v * WoP[c * 3 + 1];
        a2 += v * WoP[c * 3 + 2];
    }
    #pragma unroll
    for (int m = 1; m < 64; m <<= 1) {
        a0 += __shfl_xor(a0, m); a1 += __shfl_xor(a1, m); a2 += __shfl_xor(a2, m);
    }
    if (t == 0) {
        outp[(size_t)row * 3 + 0] = a0;
        outp[(size_t)row * 3 + 1] = a1;
        outp[(size_t)row * 3 + 2] = a2;
    }
}

extern "C" void kernel_launch(void* const* d_in, const int* in_sizes, int n_in,
                              void* d_out, int out_size, void* d_ws, size_t ws_size,
                              hipStream_t stream) {
    const float* x_source = (const float*)d_in[0];
    const float* x_out = (const float*)d_in[2];
    const float* g_s = (const float*)d_in[4];
    const float* b_s = (const float*)d_in[5];
    const float* g_o = (const float*)d_in[6];
    const float* b_o = (const float*)d_in[7];
    const float* Wq = (const float*)d_in[8];
    const float* Wk = (const float*)d_in[9];
    const float* Wv = (const float*)d_in[10];
    const float* Wo = (const float*)d_in[11];
    const float* Wp = (const float*)d_in[12];

    float* outx = (float*)d_out;                  // [BN][256]
    float* outp = outx + (size_t)BN_ * H_;        // [BN][3]

    char* ws = (char*)d_ws;
    unsigned short* f_buf = (unsigned short*)(ws);                 // 16.78 MB
    unsigned short* WcT   = (unsigned short*)(ws + 16777216);      // 786 KB
    unsigned short* WoT   = (unsigned short*)(ws + 17563648);      // 131 KB
    float*          WoP   = (float*)         (ws + 17694720);      // 3 KB
    unsigned short* qb    = (unsigned short*)(ws + 17697792);      // 8.39 MB
    unsigned short* kb    = (unsigned short*)(ws + 26086400);      // 8.39 MB
    unsigned short* vT    = (unsigned short*)(ws + 34475008);      // 8.39 MB
    unsigned short* msg   = (unsigned short*)(ws + 42863616);      // 8.39 MB

    prep<<<4096 + 1536, 256, 0, stream>>>(x_source, x_out, g_s, b_s, g_o, b_o,
                                          Wq, Wk, Wv, Wo, Wp, f_buf, WcT, WoT, WoP);
    {
        dim3 g(QKV_ / 128, BN_ / 128);
        qkv_gemm<<<g, 256, 0, stream>>>(f_buf, WcT, qb, kb, vT);
    }
    attn<<<B_ * HEADS_ * (N_ / 64), 256, 0, stream>>>(qb, kb, vT, msg);
    {
        dim3 g(H_ / 128, BN_ / 128);
        out_gemm<<<g, 256, 0, stream>>>(msg, WoT, x_out, outx);
    }
    p_kernel<<<BN_, 64, 0, stream>>>(msg, WoP, outp);
}

// Round 7
// 198.986 us; speedup vs baseline: 1.0178x; 1.0178x over previous
//
#include <hip/hip_runtime.h>
#include <hip/hip_bf16.h>

#define B_ 16
#define N_ 1024
#define H_ 256
#define HEADS_ 8
#define DH_ 32
#define BN_ (B_*N_)
#define F_ (2*H_)      // 512
#define QKV_ 768

typedef __attribute__((ext_vector_type(8))) __bf16 bf16x8;
typedef __attribute__((ext_vector_type(4))) float floatx4;

// scale(1/sqrt(32)) * log2(e): folded into q so softmax is a bare v_exp (2^x)
#define QSC 0.25506910542339896f

#if __has_builtin(__builtin_amdgcn_exp2f)
#define EXP2(x) __builtin_amdgcn_exp2f(x)
#else
#define EXP2(x) exp2f(x)
#endif

__device__ __forceinline__ unsigned short f2bf(float f) {
    union { float f; unsigned int u; } c; c.f = f;
    unsigned int u = c.u;
    return (unsigned short)((u + 0x7fffu + ((u >> 16) & 1u)) >> 16);
}
__device__ __forceinline__ float bf2f(unsigned short s) {
    union { unsigned int u; float f; } c; c.u = ((unsigned int)s) << 16;
    return c.f;
}
__device__ __forceinline__ unsigned int fbits(float f) {
    union { float f; unsigned int u; } c; c.f = f; return c.u;
}
// pack two floats to bf16x2 via v_perm (round-half-away)
__device__ __forceinline__ unsigned int pk2(float lo, float hi) {
    return __builtin_amdgcn_perm(fbits(hi) + 0x8000u, fbits(lo) + 0x8000u, 0x07060302u);
}

// async global->LDS, 16B per lane; lds dest = wave-uniform base + lane*16
__device__ __forceinline__ void async16(const void* g, void* l) {
    __builtin_amdgcn_global_load_lds(
        (const __attribute__((address_space(1))) unsigned int*)g,
        (__attribute__((address_space(3))) unsigned int*)l,
        16, 0, 0);
}

// ---------------- kernel 1: fused prep = dual LayerNorm + weight pack -----
// blocks [0,4096): LN, 4 rows/block (1 row/wave). blocks [4096,5632): pack.
__global__ __launch_bounds__(256) void prep(
        const float* __restrict__ xs_g, const float* __restrict__ xo_g,
        const float* __restrict__ gs, const float* __restrict__ bs,
        const float* __restrict__ go, const float* __restrict__ bo,
        const float* __restrict__ Wq, const float* __restrict__ Wk,
        const float* __restrict__ Wv, const float* __restrict__ Wo,
        const float* __restrict__ Wp,
        unsigned short* __restrict__ f,
        unsigned short* __restrict__ WcT, unsigned short* __restrict__ WoT,
        float* __restrict__ WoP) {
    if (blockIdx.x < 4096) {
        int t = threadIdx.x & 63;
        int row = blockIdx.x * 4 + (threadIdx.x >> 6);
        const float4 vs = ((const float4*)(xs_g + (size_t)row * H_))[t];
        const float4 vo = ((const float4*)(xo_g + (size_t)row * H_))[t];
        float s1 = vs.x + vs.y + vs.z + vs.w;
        float s2 = vs.x*vs.x + vs.y*vs.y + vs.z*vs.z + vs.w*vs.w;
        float o1 = vo.x + vo.y + vo.z + vo.w;
        float o2 = vo.x*vo.x + vo.y*vo.y + vo.z*vo.z + vo.w*vo.w;
        #pragma unroll
        for (int m = 1; m < 64; m <<= 1) {
            s1 += __shfl_xor(s1, m); s2 += __shfl_xor(s2, m);
            o1 += __shfl_xor(o1, m); o2 += __shfl_xor(o2, m);
        }
        const float inv = 1.0f / 256.0f;
        float ms = s1 * inv, vvs = s2 * inv - ms * ms;
        float mo = o1 * inv, vvo = o2 * inv - mo * mo;
        float rs = rsqrtf(vvs + 1e-5f);
        float ro = rsqrtf(vvo + 1e-5f);
        float4 g4s = ((const float4*)gs)[t];
        float4 b4s = ((const float4*)bs)[t];
        float4 g4o = ((const float4*)go)[t];
        float4 b4o = ((const float4*)bo)[t];
        ushort4 os, oo;
        os.x = f2bf((vs.x - ms) * rs * g4s.x + b4s.x);
        os.y = f2bf((vs.y - ms) * rs * g4s.y + b4s.y);
        os.z = f2bf((vs.z - ms) * rs * g4s.z + b4s.z);
        os.w = f2bf((vs.w - ms) * rs * g4s.w + b4s.w);
        oo.x = f2bf((vo.x - mo) * ro * g4o.x + b4o.x);
        oo.y = f2bf((vo.y - mo) * ro * g4o.y + b4o.y);
        oo.z = f2bf((vo.z - mo) * ro * g4o.z + b4o.z);
        oo.w = f2bf((vo.w - mo) * ro * g4o.w + b4o.w);
        *(ushort4*)(f + (size_t)row * F_ + 4 * t) = os;
        *(ushort4*)(f + (size_t)row * F_ + H_ + 4 * t) = oo;
    } else {
        int i = (blockIdx.x - 4096) * 256 + threadIdx.x;
        const int total1 = QKV_ * F_;   // WcT[n][k]
        if (i < total1) {
            int n = i / F_, k = i % F_;
            float w;
            if (n < 256)      w = Wq[(size_t)k * H_ + n];
            else if (n < 512) w = Wk[(size_t)k * H_ + (n - 256)];
            else              w = Wv[(size_t)k * H_ + (n - 512)];
            WcT[i] = f2bf(w);
        }
        const int total2 = H_ * H_;     // WoT[n][k]
        if (i < total2) {
            int n = i / H_, k = i % H_;
            WoT[i] = f2bf(Wo[(size_t)k * H_ + n]);
        }
        if (i < H_ * 3) {               // WoP = Wo @ Wp folded
            int c = i / 3, j = i % 3;
            float s = 0.f;
            for (int n = 0; n < H_; ++n) s += Wo[(size_t)c * H_ + n] * Wp[n * 3 + j];
            WoP[i] = s;
        }
    }
}

// ---------------- kernel 2: QKV GEMM (128x128 LDS tile) -------------------
// q-section accumulators are prescaled by QSC so attn's softmax is 2^s.
__global__ __launch_bounds__(256) void qkv_gemm(
        const unsigned short* __restrict__ f,
        const unsigned short* __restrict__ WcT,
        unsigned short* __restrict__ qb,
        unsigned short* __restrict__ kb,
        unsigned short* __restrict__ vT) {
    __shared__ __align__(16) unsigned short As[128 * 32];
    __shared__ __align__(16) unsigned short Bs[128 * 32];
    int t = threadIdx.x;
    int w = t >> 6, lane = t & 63;
    int r = lane & 15, qd = lane >> 4;
    int wm = (w >> 1) * 64, wn = (w & 1) * 64;
    int m0 = blockIdx.y * 128, n0 = blockIdx.x * 128;
    int lrow = lane >> 2, lcol = (lane & 3) * 8;
    floatx4 acc[4][4] = {};
    const unsigned short* gA = f   + (size_t)(m0 + w * 32 + lrow) * F_ + lcol;
    const unsigned short* gB = WcT + (size_t)(n0 + w * 32 + lrow) * F_ + lcol;
    unsigned short* lA = As + (w * 32) * 32;
    unsigned short* lB = Bs + (w * 32) * 32;
    for (int k0 = 0; k0 < F_; k0 += 32) {
        async16(gA + k0,            lA);
        async16(gA + k0 + 16 * F_,  lA + 16 * 32);
        async16(gB + k0,            lB);
        async16(gB + k0 + 16 * F_,  lB + 16 * 32);
        __syncthreads();
        bf16x8 aF[4], bF[4];
        #pragma unroll
        for (int mt = 0; mt < 4; ++mt)
            aF[mt] = *(const bf16x8*)(As + (wm + mt * 16 + r) * 32 + qd * 8);
        #pragma unroll
        for (int nt = 0; nt < 4; ++nt)
            bF[nt] = *(const bf16x8*)(Bs + (wn + nt * 16 + r) * 32 + qd * 8);
        #pragma unroll
        for (int mt = 0; mt < 4; ++mt)
            #pragma unroll
            for (int nt = 0; nt < 4; ++nt)
                acc[mt][nt] = __builtin_amdgcn_mfma_f32_16x16x32_bf16(aF[mt], bF[nt], acc[mt][nt], 0, 0, 0);
        __syncthreads();
    }
    #pragma unroll
    for (int nt = 0; nt < 4; ++nt) {
        int cg = n0 + wn + nt * 16 + r;
        int sec = cg >> 8;              // 0=q 1=k 2=v
        int hh = (cg >> 5) & 7;
        int d = cg & 31;
        #pragma unroll
        for (int mt = 0; mt < 4; ++mt) {
            int tok = m0 + wm + mt * 16 + qd * 4;
            int b = tok >> 10, tl = tok & 1023;
            size_t hb = (size_t)b * 8 + hh;
            if (sec == 0) {
                unsigned short* p = qb + (hb * 1024 + tl) * 32 + d;
                #pragma unroll
                for (int i = 0; i < 4; ++i) p[i * 32] = f2bf(acc[mt][nt][i] * QSC);
            } else if (sec == 1) {
                unsigned short* p = kb + (hb * 1024 + tl) * 32 + d;
                #pragma unroll
                for (int i = 0; i < 4; ++i) p[i * 32] = f2bf(acc[mt][nt][i]);
            } else {
                ushort4 v4;
                v4.x = f2bf(acc[mt][nt][0]); v4.y = f2bf(acc[mt][nt][1]);
                v4.z = f2bf(acc[mt][nt][2]); v4.w = f2bf(acc[mt][nt][3]);
                *(ushort4*)(vT + (hb * 32 + d) * 1024 + tl) = v4;
            }
        }
    }
}

// ---------------- kernel 3: flash attention, split-K across waves ---------
// Block = 64 q-rows x one (b,h). Wave w handles keys [w*256,(w+1)*256) for
// ALL 64 q-rows (no redundant K/V reads across waves). Partial O/l combined
// through LDS (fp32 — measured best in R5). Fixed-max softmax, l via
// ones-MFMA.
__global__ __launch_bounds__(256) void attn(
        const unsigned short* __restrict__ qb,
        const unsigned short* __restrict__ kb,
        const unsigned short* __restrict__ vT,
        unsigned short* __restrict__ msg) {
    __shared__ float ob[4][32][66];     // [wave][d][q] transposed partials
    __shared__ float lb[4][64];         // [wave][q] row-sum partials
    int blk = blockIdx.x;
    int qt = blk & 15;
    int h  = (blk >> 4) & 7;
    int b  = blk >> 7;
    int t = threadIdx.x;
    int w = t >> 6, lane = t & 63;
    int r = lane & 15, qd = lane >> 4;
    int q0 = qt * 64;
    size_t hb = (size_t)b * 8 + h;
    const unsigned short* qs = qb + hb * (1024 * 32);
    const unsigned short* ks = kb + hb * (1024 * 32);
    const unsigned short* vs = vT + hb * (32 * 1024);
    bf16x8 qf[4];
    #pragma unroll
    for (int i = 0; i < 4; ++i)
        qf[i] = *(const bf16x8*)(qs + (size_t)(q0 + i * 16 + r) * 32 + qd * 8);
    union { unsigned int u[4]; bf16x8 v; } onesu;
    onesu.u[0] = onesu.u[1] = onesu.u[2] = onesu.u[3] = 0x3F803F80u;
    const bf16x8 onesv = onesu.v;
    floatx4 o0[4] = {}, o1[4] = {}, ol[4] = {};
    int srcA = ((qd & 1) * 2) * 16 + r;
    int srcB = srcA + 16;
    bool hiq = qd >= 2;
    int kb0 = w * 256;
    for (int kc = 0; kc < 256; kc += 32) {
        int kk = kb0 + kc;
        bf16x8 kf0 = *(const bf16x8*)(ks + (size_t)(kk + r) * 32 + qd * 8);
        bf16x8 kf1 = *(const bf16x8*)(ks + (size_t)(kk + 16 + r) * 32 + qd * 8);
        bf16x8 vf0 = *(const bf16x8*)(vs + (size_t)r * 1024 + kk + qd * 8);
        bf16x8 vf1 = *(const bf16x8*)(vs + (size_t)(16 + r) * 1024 + kk + qd * 8);
        #pragma unroll
        for (int i = 0; i < 4; ++i) {
            floatx4 z = {0.f,0.f,0.f,0.f};
            floatx4 s0 = __builtin_amdgcn_mfma_f32_16x16x32_bf16(kf0, qf[i], z, 0, 0, 0);
            floatx4 s1 = __builtin_amdgcn_mfma_f32_16x16x32_bf16(kf1, qf[i], z, 0, 0, 0);
            float e0[4], e1[4];
            #pragma unroll
            for (int j = 0; j < 4; ++j) {
                e0[j] = EXP2(s0[j]);
                e1[j] = EXP2(s1[j]);
            }
            unsigned int t00 = pk2(e0[0], e0[1]), t01 = pk2(e0[2], e0[3]);
            unsigned int t10 = pk2(e1[0], e1[1]), t11 = pk2(e1[2], e1[3]);
            unsigned int a0 = __shfl((int)t00, srcA), a1 = __shfl((int)t01, srcA);
            unsigned int b0 = __shfl((int)t00, srcB), b1 = __shfl((int)t01, srcB);
            unsigned int c0 = __shfl((int)t10, srcA), c1 = __shfl((int)t11, srcA);
            unsigned int d0 = __shfl((int)t10, srcB), d1 = __shfl((int)t11, srcB);
            union { unsigned int u[4]; bf16x8 v; } pf;
            pf.u[0] = hiq ? c0 : a0;
            pf.u[1] = hiq ? c1 : a1;
            pf.u[2] = hiq ? d0 : b0;
            pf.u[3] = hiq ? d1 : b1;
            o0[i] = __builtin_amdgcn_mfma_f32_16x16x32_bf16(vf0, pf.v, o0[i], 0, 0, 0);
            o1[i] = __builtin_amdgcn_mfma_f32_16x16x32_bf16(vf1, pf.v, o1[i], 0, 0, 0);
            ol[i] = __builtin_amdgcn_mfma_f32_16x16x32_bf16(onesv, pf.v, ol[i], 0, 0, 0);
        }
    }
    // write per-wave partials: O^T C-layout lane holds d=qd*4+j (o0) /
    // 16+qd*4+j (o1), q=r for tile i. Transposed LDS [d][q], 2-way max.
    #pragma unroll
    for (int i = 0; i < 4; ++i) {
        #pragma unroll
        for (int j = 0; j < 4; ++j) {
            ob[w][qd * 4 + j][i * 16 + r]      = o0[i][j];
            ob[w][16 + qd * 4 + j][i * 16 + r] = o1[i][j];
        }
        if (qd == 0) lb[w][i * 16 + r] = ol[i][0];
    }
    __syncthreads();
    // final: thread (q2 = t>>2, dg = t&3) reduces 8 d-elems of one q-row
    {
        int q2 = t >> 2, dg = t & 3;
        float acc8[8] = {0.f,0.f,0.f,0.f,0.f,0.f,0.f,0.f};
        float L = 0.f;
        #pragma unroll
        for (int ww = 0; ww < 4; ++ww) {
            L += lb[ww][q2];
            #pragma unroll
            for (int j = 0; j < 8; ++j)
                acc8[j] += ob[ww][dg * 8 + j][q2];
        }
        float rinv = 1.0f / L;
        uint4 pkd;
        pkd.x = pk2(acc8[0] * rinv, acc8[1] * rinv);
        pkd.y = pk2(acc8[2] * rinv, acc8[3] * rinv);
        pkd.z = pk2(acc8[4] * rinv, acc8[5] * rinv);
        pkd.w = pk2(acc8[6] * rinv, acc8[7] * rinv);
        *(uint4*)(msg + ((size_t)(b * N_ + q0 + q2)) * H_ + h * DH_ + dg * 8) = pkd;
    }
}

// ---------------- kernel 4: Wo GEMM + residual (64x64 tile, 4 blk/CU) -----
// grid (H_/64, BN_/64) = (4, 256) = 1024 blocks. Wave w owns a 32x32
// quadrant (2x2 MFMA subtiles). K = 256 -> 8 iters, 1 async16/thread/iter.
__global__ __launch_bounds__(256) void out_gemm(
        const unsigned short* __restrict__ msg,
        const unsigned short* __restrict__ WoT,
        const float* __restrict__ x_out,
        float* __restrict__ outx) {
    __shared__ __align__(16) unsigned short As[64 * 32];
    __shared__ __align__(16) unsigned short Bs[64 * 32];
    int t = threadIdx.x;
    int w = t >> 6, lane = t & 63;
    int r = lane & 15, qd = lane >> 4;
    int wm = (w >> 1) * 32, wn = (w & 1) * 32;
    int m0 = blockIdx.y * 64, n0 = blockIdx.x * 64;
    int lrow = lane >> 2, lcol = (lane & 3) * 8;   // 16 rows x 32 cols per wave
    floatx4 acc[2][2] = {};
    const unsigned short* gA = msg + (size_t)(m0 + w * 16 + lrow) * H_ + lcol;
    const unsigned short* gB = WoT + (size_t)(n0 + w * 16 + lrow) * H_ + lcol;
    unsigned short* lA = As + (w * 16) * 32;
    unsigned short* lB = Bs + (w * 16) * 32;
    for (int k0 = 0; k0 < H_; k0 += 32) {
        async16(gA + k0, lA);
        async16(gB + k0, lB);
        __syncthreads();
        bf16x8 aF[2], bF[2];
        #pragma unroll
        for (int mt = 0; mt < 2; ++mt)
            aF[mt] = *(const bf16x8*)(As + (wm + mt * 16 + r) * 32 + qd * 8);
        #pragma unroll
        for (int nt = 0; nt < 2; ++nt)
            bF[nt] = *(const bf16x8*)(Bs + (wn + nt * 16 + r) * 32 + qd * 8);
        #pragma unroll
        for (int mt = 0; mt < 2; ++mt)
            #pragma unroll
            for (int nt = 0; nt < 2; ++nt)
                acc[mt][nt] = __builtin_amdgcn_mfma_f32_16x16x32_bf16(aF[mt], bF[nt], acc[mt][nt], 0, 0, 0);
        __syncthreads();
    }
    #pragma unroll
    for (int nt = 0; nt < 2; ++nt) {
        int cg = n0 + wn + nt * 16 + r;
        #pragma unroll
        for (int mt = 0; mt < 2; ++mt) {
            int tok = m0 + wm + mt * 16 + qd * 4;
            #pragma unroll
            for (int i = 0; i < 4; ++i) {
                size_t idx = (size_t)(tok + i) * H_ + cg;
                outx[idx] = x_out[idx] + acc[mt][nt][i];
            }
        }
    }
}

// ---------------- kernel 5: position head  p = msg @ WoP ------------------
__global__ __launch_bounds__(64) void p_kernel(
        const unsigned short* __restrict__ msg, const float* __restrict__ WoP,
        float* __restrict__ outp) {
    int row = blockIdx.x;
    int t = threadIdx.x;
    float a0 = 0.f, a1 = 0.f, a2 = 0.f;
    #pragma unroll
    for (int i = 0; i < 4; ++i) {
        int c = t + 64 * i;
        float v = bf2f(msg[(size_t)row * H_ + c]);
        a0 += v * WoP[c * 3 + 0];
        a1 += v * WoP[c * 3 + 1];
        a2 += v * WoP[c * 3 + 2];
    }
    #pragma unroll
    for (int m = 1; m < 64; m <<= 1) {
        a0 += __shfl_xor(a0, m); a1 += __shfl_xor(a1, m); a2 += __shfl_xor(a2, m);
    }
    if (t == 0) {
        outp[(size_t)row * 3 + 0] = a0;
        outp[(size_t)row * 3 + 1] = a1;
        outp[(size_t)row * 3 + 2] = a2;
    }
}

extern "C" void kernel_launch(void* const* d_in, const int* in_sizes, int n_in,
                              void* d_out, int out_size, void* d_ws, size_t ws_size,
                              hipStream_t stream) {
    const float* x_source = (const float*)d_in[0];
    const float* x_out = (const float*)d_in[2];
    const float* g_s = (const float*)d_in[4];
    const float* b_s = (const float*)d_in[5];
    const float* g_o = (const float*)d_in[6];
    const float* b_o = (const float*)d_in[7];
    const float* Wq = (const float*)d_in[8];
    const float* Wk = (const float*)d_in[9];
    const float* Wv = (const float*)d_in[10];
    const float* Wo = (const float*)d_in[11];
    const float* Wp = (const float*)d_in[12];

    float* outx = (float*)d_out;                  // [BN][256]
    float* outp = outx + (size_t)BN_ * H_;        // [BN][3]

    char* ws = (char*)d_ws;
    unsigned short* f_buf = (unsigned short*)(ws);                 // 16.78 MB
    unsigned short* WcT   = (unsigned short*)(ws + 16777216);      // 786 KB
    unsigned short* WoT   = (unsigned short*)(ws + 17563648);      // 131 KB
    float*          WoP   = (float*)         (ws + 17694720);      // 3 KB
    unsigned short* qb    = (unsigned short*)(ws + 17697792);      // 8.39 MB
    unsigned short* kb    = (unsigned short*)(ws + 26086400);      // 8.39 MB
    unsigned short* vT    = (unsigned short*)(ws + 34475008);      // 8.39 MB
    unsigned short* msg   = (unsigned short*)(ws + 42863616);      // 8.39 MB

    prep<<<4096 + 1536, 256, 0, stream>>>(x_source, x_out, g_s, b_s, g_o, b_o,
                                          Wq, Wk, Wv, Wo, Wp, f_buf, WcT, WoT, WoP);
    {
        dim3 g(QKV_ / 128, BN_ / 128);
        qkv_gemm<<<g, 256, 0, stream>>>(f_buf, WcT, qb, kb, vT);
    }
    attn<<<B_ * HEADS_ * (N_ / 64), 256, 0, stream>>>(qb, kb, vT, msg);
    {
        dim3 g(H_ / 64, BN_ / 64);
        out_gemm<<<g, 256, 0, stream>>>(msg, WoT, x_out, outx);
    }
    p_kernel<<<BN_, 64, 0, stream>>>(msg, WoP, outp);
}

// Round 8
// 194.719 us; speedup vs baseline: 1.0401x; 1.0219x over previous
//
#include <hip/hip_runtime.h>
#include <hip/hip_bf16.h>

#define B_ 16
#define N_ 1024
#define H_ 256
#define HEADS_ 8
#define DH_ 32
#define BN_ (B_*N_)
#define F_ (2*H_)      // 512
#define QKV_ 768

typedef __attribute__((ext_vector_type(8))) __bf16 bf16x8;
typedef __attribute__((ext_vector_type(4))) float floatx4;

// scale(1/sqrt(32)) * log2(e): folded into q so softmax is a bare v_exp (2^x)
#define QSC 0.25506910542339896f

#if __has_builtin(__builtin_amdgcn_exp2f)
#define EXP2(x) __builtin_amdgcn_exp2f(x)
#else
#define EXP2(x) exp2f(x)
#endif

__device__ __forceinline__ unsigned short f2bf(float f) {
    union { float f; unsigned int u; } c; c.f = f;
    unsigned int u = c.u;
    return (unsigned short)((u + 0x7fffu + ((u >> 16) & 1u)) >> 16);
}
__device__ __forceinline__ float bf2f(unsigned short s) {
    union { unsigned int u; float f; } c; c.u = ((unsigned int)s) << 16;
    return c.f;
}
__device__ __forceinline__ unsigned int fbits(float f) {
    union { float f; unsigned int u; } c; c.f = f; return c.u;
}
// pack two floats to bf16x2 via v_perm (round-half-away) — epilogue use
__device__ __forceinline__ unsigned int pk2(float lo, float hi) {
    return __builtin_amdgcn_perm(fbits(hi) + 0x8000u, fbits(lo) + 0x8000u, 0x07060302u);
}
// fast pack for the attn inner loop: hw packed cvt if present, else truncate
// (truncation bias cancels in O = sum(p v)/sum(p) since l uses same p)
__device__ __forceinline__ unsigned int pkp(float lo, float hi) {
#if __has_builtin(__builtin_amdgcn_cvt_pk_bf16_f32)
    typedef __attribute__((ext_vector_type(2))) __bf16 bf2;
    union { bf2 v; unsigned int u; } c;
    c.v = __builtin_amdgcn_cvt_pk_bf16_f32(lo, hi);
    return c.u;
#else
    return __builtin_amdgcn_perm(fbits(hi), fbits(lo), 0x07060302u);
#endif
}

// async global->LDS, 16B per lane; lds dest = wave-uniform base + lane*16
__device__ __forceinline__ void async16(const void* g, void* l) {
    __builtin_amdgcn_global_load_lds(
        (const __attribute__((address_space(1))) unsigned int*)g,
        (__attribute__((address_space(3))) unsigned int*)l,
        16, 0, 0);
}

// ---------------- kernel 1: fused prep = dual LayerNorm + weight pack -----
// blocks [0,4096): LN, 4 rows/block (1 row/wave). blocks [4096,5632): pack.
__global__ __launch_bounds__(256) void prep(
        const float* __restrict__ xs_g, const float* __restrict__ xo_g,
        const float* __restrict__ gs, const float* __restrict__ bs,
        const float* __restrict__ go, const float* __restrict__ bo,
        const float* __restrict__ Wq, const float* __restrict__ Wk,
        const float* __restrict__ Wv, const float* __restrict__ Wo,
        const float* __restrict__ Wp,
        unsigned short* __restrict__ f,
        unsigned short* __restrict__ WcT, unsigned short* __restrict__ WoT,
        unsigned short* __restrict__ WpT) {
    if (blockIdx.x < 4096) {
        int t = threadIdx.x & 63;
        int row = blockIdx.x * 4 + (threadIdx.x >> 6);
        const float4 vs = ((const float4*)(xs_g + (size_t)row * H_))[t];
        const float4 vo = ((const float4*)(xo_g + (size_t)row * H_))[t];
        float s1 = vs.x + vs.y + vs.z + vs.w;
        float s2 = vs.x*vs.x + vs.y*vs.y + vs.z*vs.z + vs.w*vs.w;
        float o1 = vo.x + vo.y + vo.z + vo.w;
        float o2 = vo.x*vo.x + vo.y*vo.y + vo.z*vo.z + vo.w*vo.w;
        #pragma unroll
        for (int m = 1; m < 64; m <<= 1) {
            s1 += __shfl_xor(s1, m); s2 += __shfl_xor(s2, m);
            o1 += __shfl_xor(o1, m); o2 += __shfl_xor(o2, m);
        }
        const float inv = 1.0f / 256.0f;
        float ms = s1 * inv, vvs = s2 * inv - ms * ms;
        float mo = o1 * inv, vvo = o2 * inv - mo * mo;
        float rs = rsqrtf(vvs + 1e-5f);
        float ro = rsqrtf(vvo + 1e-5f);
        float4 g4s = ((const float4*)gs)[t];
        float4 b4s = ((const float4*)bs)[t];
        float4 g4o = ((const float4*)go)[t];
        float4 b4o = ((const float4*)bo)[t];
        ushort4 os, oo;
        os.x = f2bf((vs.x - ms) * rs * g4s.x + b4s.x);
        os.y = f2bf((vs.y - ms) * rs * g4s.y + b4s.y);
        os.z = f2bf((vs.z - ms) * rs * g4s.z + b4s.z);
        os.w = f2bf((vs.w - ms) * rs * g4s.w + b4s.w);
        oo.x = f2bf((vo.x - mo) * ro * g4o.x + b4o.x);
        oo.y = f2bf((vo.y - mo) * ro * g4o.y + b4o.y);
        oo.z = f2bf((vo.z - mo) * ro * g4o.z + b4o.z);
        oo.w = f2bf((vo.w - mo) * ro * g4o.w + b4o.w);
        *(ushort4*)(f + (size_t)row * F_ + 4 * t) = os;
        *(ushort4*)(f + (size_t)row * F_ + H_ + 4 * t) = oo;
    } else {
        int i = (blockIdx.x - 4096) * 256 + threadIdx.x;
        const int total1 = QKV_ * F_;   // WcT[n][k]
        if (i < total1) {
            int n = i / F_, k = i % F_;
            float w;
            if (n < 256)      w = Wq[(size_t)k * H_ + n];
            else if (n < 512) w = Wk[(size_t)k * H_ + (n - 256)];
            else              w = Wv[(size_t)k * H_ + (n - 512)];
            WcT[i] = f2bf(w);
        }
        const int total2 = H_ * H_;     // WoT[n][k]
        if (i < total2) {
            int n = i / H_, k = i % H_;
            WoT[i] = f2bf(Wo[(size_t)k * H_ + n]);
        }
        if (i < 16 * H_) {              // WpT[n][k] = (Wo @ Wp)^T bf16, n<3
            int n = i >> 8, k = i & 255;
            if (n < 3) {
                float s = 0.f;
                for (int m = 0; m < H_; ++m) s += Wo[(size_t)k * H_ + m] * Wp[m * 3 + n];
                WpT[i] = f2bf(s);
            } else {
                WpT[i] = 0;
            }
        }
    }
}

// ---------------- kernel 2: QKV GEMM (128x128 LDS tile) -------------------
// q-section accumulators are prescaled by QSC so attn's softmax is 2^s.
__global__ __launch_bounds__(256) void qkv_gemm(
        const unsigned short* __restrict__ f,
        const unsigned short* __restrict__ WcT,
        unsigned short* __restrict__ qb,
        unsigned short* __restrict__ kb,
        unsigned short* __restrict__ vT) {
    __shared__ __align__(16) unsigned short As[128 * 32];
    __shared__ __align__(16) unsigned short Bs[128 * 32];
    int t = threadIdx.x;
    int w = t >> 6, lane = t & 63;
    int r = lane & 15, qd = lane >> 4;
    int wm = (w >> 1) * 64, wn = (w & 1) * 64;
    int m0 = blockIdx.y * 128, n0 = blockIdx.x * 128;
    int lrow = lane >> 2, lcol = (lane & 3) * 8;
    floatx4 acc[4][4] = {};
    const unsigned short* gA = f   + (size_t)(m0 + w * 32 + lrow) * F_ + lcol;
    const unsigned short* gB = WcT + (size_t)(n0 + w * 32 + lrow) * F_ + lcol;
    unsigned short* lA = As + (w * 32) * 32;
    unsigned short* lB = Bs + (w * 32) * 32;
    for (int k0 = 0; k0 < F_; k0 += 32) {
        async16(gA + k0,            lA);
        async16(gA + k0 + 16 * F_,  lA + 16 * 32);
        async16(gB + k0,            lB);
        async16(gB + k0 + 16 * F_,  lB + 16 * 32);
        __syncthreads();
        bf16x8 aF[4], bF[4];
        #pragma unroll
        for (int mt = 0; mt < 4; ++mt)
            aF[mt] = *(const bf16x8*)(As + (wm + mt * 16 + r) * 32 + qd * 8);
        #pragma unroll
        for (int nt = 0; nt < 4; ++nt)
            bF[nt] = *(const bf16x8*)(Bs + (wn + nt * 16 + r) * 32 + qd * 8);
        #pragma unroll
        for (int mt = 0; mt < 4; ++mt)
            #pragma unroll
            for (int nt = 0; nt < 4; ++nt)
                acc[mt][nt] = __builtin_amdgcn_mfma_f32_16x16x32_bf16(aF[mt], bF[nt], acc[mt][nt], 0, 0, 0);
        __syncthreads();
    }
    #pragma unroll
    for (int nt = 0; nt < 4; ++nt) {
        int cg = n0 + wn + nt * 16 + r;
        int sec = cg >> 8;              // 0=q 1=k 2=v
        int hh = (cg >> 5) & 7;
        int d = cg & 31;
        #pragma unroll
        for (int mt = 0; mt < 4; ++mt) {
            int tok = m0 + wm + mt * 16 + qd * 4;
            int b = tok >> 10, tl = tok & 1023;
            size_t hb = (size_t)b * 8 + hh;
            if (sec == 0) {
                unsigned short* p = qb + (hb * 1024 + tl) * 32 + d;
                #pragma unroll
                for (int i = 0; i < 4; ++i) p[i * 32] = f2bf(acc[mt][nt][i] * QSC);
            } else if (sec == 1) {
                unsigned short* p = kb + (hb * 1024 + tl) * 32 + d;
                #pragma unroll
                for (int i = 0; i < 4; ++i) p[i * 32] = f2bf(acc[mt][nt][i]);
            } else {
                ushort4 v4;
                v4.x = f2bf(acc[mt][nt][0]); v4.y = f2bf(acc[mt][nt][1]);
                v4.z = f2bf(acc[mt][nt][2]); v4.w = f2bf(acc[mt][nt][3]);
                *(ushort4*)(vT + (hb * 32 + d) * 1024 + tl) = v4;
            }
        }
    }
}

// ---------------- kernel 3: flash attention, split-K across waves ---------
// Block = 64 q-rows x one (b,h). Wave w handles keys [w*256,(w+1)*256) for
// ALL 64 q-rows. fp32 partials through LDS (measured best, R5). Fixed-max
// softmax, l via ones-MFMA, fast bf16 pack in the hot loop.
__global__ __launch_bounds__(256) void attn(
        const unsigned short* __restrict__ qb,
        const unsigned short* __restrict__ kb,
        const unsigned short* __restrict__ vT,
        unsigned short* __restrict__ msg) {
    __shared__ float ob[4][32][66];     // [wave][d][q] transposed partials
    __shared__ float lb[4][64];         // [wave][q] row-sum partials
    int blk = blockIdx.x;
    int qt = blk & 15;
    int h  = (blk >> 4) & 7;
    int b  = blk >> 7;
    int t = threadIdx.x;
    int w = t >> 6, lane = t & 63;
    int r = lane & 15, qd = lane >> 4;
    int q0 = qt * 64;
    size_t hb = (size_t)b * 8 + h;
    const unsigned short* qs = qb + hb * (1024 * 32);
    const unsigned short* ks = kb + hb * (1024 * 32);
    const unsigned short* vs = vT + hb * (32 * 1024);
    bf16x8 qf[4];
    #pragma unroll
    for (int i = 0; i < 4; ++i)
        qf[i] = *(const bf16x8*)(qs + (size_t)(q0 + i * 16 + r) * 32 + qd * 8);
    union { unsigned int u[4]; bf16x8 v; } onesu;
    onesu.u[0] = onesu.u[1] = onesu.u[2] = onesu.u[3] = 0x3F803F80u;
    const bf16x8 onesv = onesu.v;
    floatx4 o0[4] = {}, o1[4] = {}, ol[4] = {};
    int srcA = ((qd & 1) * 2) * 16 + r;
    int srcB = srcA + 16;
    bool hiq = qd >= 2;
    int kb0 = w * 256;
    for (int kc = 0; kc < 256; kc += 32) {
        int kk = kb0 + kc;
        bf16x8 kf0 = *(const bf16x8*)(ks + (size_t)(kk + r) * 32 + qd * 8);
        bf16x8 kf1 = *(const bf16x8*)(ks + (size_t)(kk + 16 + r) * 32 + qd * 8);
        bf16x8 vf0 = *(const bf16x8*)(vs + (size_t)r * 1024 + kk + qd * 8);
        bf16x8 vf1 = *(const bf16x8*)(vs + (size_t)(16 + r) * 1024 + kk + qd * 8);
        #pragma unroll
        for (int i = 0; i < 4; ++i) {
            floatx4 z = {0.f,0.f,0.f,0.f};
            floatx4 s0 = __builtin_amdgcn_mfma_f32_16x16x32_bf16(kf0, qf[i], z, 0, 0, 0);
            floatx4 s1 = __builtin_amdgcn_mfma_f32_16x16x32_bf16(kf1, qf[i], z, 0, 0, 0);
            float e0[4], e1[4];
            #pragma unroll
            for (int j = 0; j < 4; ++j) {
                e0[j] = EXP2(s0[j]);
                e1[j] = EXP2(s1[j]);
            }
            unsigned int t00 = pkp(e0[0], e0[1]), t01 = pkp(e0[2], e0[3]);
            unsigned int t10 = pkp(e1[0], e1[1]), t11 = pkp(e1[2], e1[3]);
            unsigned int a0 = __shfl((int)t00, srcA), a1 = __shfl((int)t01, srcA);
            unsigned int b0 = __shfl((int)t00, srcB), b1 = __shfl((int)t01, srcB);
            unsigned int c0 = __shfl((int)t10, srcA), c1 = __shfl((int)t11, srcA);
            unsigned int d0 = __shfl((int)t10, srcB), d1 = __shfl((int)t11, srcB);
            union { unsigned int u[4]; bf16x8 v; } pf;
            pf.u[0] = hiq ? c0 : a0;
            pf.u[1] = hiq ? c1 : a1;
            pf.u[2] = hiq ? d0 : b0;
            pf.u[3] = hiq ? d1 : b1;
            o0[i] = __builtin_amdgcn_mfma_f32_16x16x32_bf16(vf0, pf.v, o0[i], 0, 0, 0);
            o1[i] = __builtin_amdgcn_mfma_f32_16x16x32_bf16(vf1, pf.v, o1[i], 0, 0, 0);
            ol[i] = __builtin_amdgcn_mfma_f32_16x16x32_bf16(onesv, pf.v, ol[i], 0, 0, 0);
        }
    }
    #pragma unroll
    for (int i = 0; i < 4; ++i) {
        #pragma unroll
        for (int j = 0; j < 4; ++j) {
            ob[w][qd * 4 + j][i * 16 + r]      = o0[i][j];
            ob[w][16 + qd * 4 + j][i * 16 + r] = o1[i][j];
        }
        if (qd == 0) lb[w][i * 16 + r] = ol[i][0];
    }
    __syncthreads();
    {
        int q2 = t >> 2, dg = t & 3;
        float acc8[8] = {0.f,0.f,0.f,0.f,0.f,0.f,0.f,0.f};
        float L = 0.f;
        #pragma unroll
        for (int ww = 0; ww < 4; ++ww) {
            L += lb[ww][q2];
            #pragma unroll
            for (int j = 0; j < 8; ++j)
                acc8[j] += ob[ww][dg * 8 + j][q2];
        }
        float rinv = 1.0f / L;
        uint4 pkd;
        pkd.x = pk2(acc8[0] * rinv, acc8[1] * rinv);
        pkd.y = pk2(acc8[2] * rinv, acc8[3] * rinv);
        pkd.z = pk2(acc8[4] * rinv, acc8[5] * rinv);
        pkd.w = pk2(acc8[6] * rinv, acc8[7] * rinv);
        *(uint4*)(msg + ((size_t)(b * N_ + q0 + q2)) * H_ + h * DH_ + dg * 8) = pkd;
    }
}

// ---------------- kernel 4: Wo GEMM + residual + fused p head -------------
// grid (H_/64, BN_/64). Waves with wn==0 also accumulate p = msg @ WpT^T
// (WpT rows >=3 are zero) and store p for their token rows.
__global__ __launch_bounds__(256) void out_gemm(
        const unsigned short* __restrict__ msg,
        const unsigned short* __restrict__ WoT,
        const unsigned short* __restrict__ WpT,
        const float* __restrict__ x_out,
        float* __restrict__ outx, float* __restrict__ outp) {
    __shared__ __align__(16) unsigned short As[64 * 32];
    __shared__ __align__(16) unsigned short Bs[64 * 32];
    int t = threadIdx.x;
    int w = t >> 6, lane = t & 63;
    int r = lane & 15, qd = lane >> 4;
    int wm = (w >> 1) * 32, wn = (w & 1) * 32;
    int m0 = blockIdx.y * 64, n0 = blockIdx.x * 64;
    int lrow = lane >> 2, lcol = (lane & 3) * 8;
    bool do_p = (blockIdx.x == 0) && ((w & 1) == 0);
    floatx4 acc[2][2] = {};
    floatx4 accp[2] = {};
    const unsigned short* gA = msg + (size_t)(m0 + w * 16 + lrow) * H_ + lcol;
    const unsigned short* gB = WoT + (size_t)(n0 + w * 16 + lrow) * H_ + lcol;
    unsigned short* lA = As + (w * 16) * 32;
    unsigned short* lB = Bs + (w * 16) * 32;
    for (int k0 = 0; k0 < H_; k0 += 32) {
        async16(gA + k0, lA);
        async16(gB + k0, lB);
        __syncthreads();
        bf16x8 aF[2], bF[2];
        #pragma unroll
        for (int mt = 0; mt < 2; ++mt)
            aF[mt] = *(const bf16x8*)(As + (wm + mt * 16 + r) * 32 + qd * 8);
        #pragma unroll
        for (int nt = 0; nt < 2; ++nt)
            bF[nt] = *(const bf16x8*)(Bs + (wn + nt * 16 + r) * 32 + qd * 8);
        #pragma unroll
        for (int mt = 0; mt < 2; ++mt)
            #pragma unroll
            for (int nt = 0; nt < 2; ++nt)
                acc[mt][nt] = __builtin_amdgcn_mfma_f32_16x16x32_bf16(aF[mt], bF[nt], acc[mt][nt], 0, 0, 0);
        if (do_p) {
            bf16x8 bP = *(const bf16x8*)(WpT + (size_t)r * H_ + k0 + qd * 8);
            #pragma unroll
            for (int mt = 0; mt < 2; ++mt)
                accp[mt] = __builtin_amdgcn_mfma_f32_16x16x32_bf16(aF[mt], bP, accp[mt], 0, 0, 0);
        }
        __syncthreads();
    }
    #pragma unroll
    for (int nt = 0; nt < 2; ++nt) {
        int cg = n0 + wn + nt * 16 + r;
        #pragma unroll
        for (int mt = 0; mt < 2; ++mt) {
            int tok = m0 + wm + mt * 16 + qd * 4;
            #pragma unroll
            for (int i = 0; i < 4; ++i) {
                size_t idx = (size_t)(tok + i) * H_ + cg;
                outx[idx] = x_out[idx] + acc[mt][nt][i];
            }
        }
    }
    if (do_p && r < 3) {
        #pragma unroll
        for (int mt = 0; mt < 2; ++mt) {
            int tok = m0 + wm + mt * 16 + qd * 4;
            #pragma unroll
            for (int i = 0; i < 4; ++i)
                outp[(size_t)(tok + i) * 3 + r] = accp[mt][i];
        }
    }
}

extern "C" void kernel_launch(void* const* d_in, const int* in_sizes, int n_in,
                              void* d_out, int out_size, void* d_ws, size_t ws_size,
                              hipStream_t stream) {
    const float* x_source = (const float*)d_in[0];
    const float* x_out = (const float*)d_in[2];
    const float* g_s = (const float*)d_in[4];
    const float* b_s = (const float*)d_in[5];
    const float* g_o = (const float*)d_in[6];
    const float* b_o = (const float*)d_in[7];
    const float* Wq = (const float*)d_in[8];
    const float* Wk = (const float*)d_in[9];
    const float* Wv = (const float*)d_in[10];
    const float* Wo = (const float*)d_in[11];
    const float* Wp = (const float*)d_in[12];

    float* outx = (float*)d_out;                  // [BN][256]
    float* outp = outx + (size_t)BN_ * H_;        // [BN][3]

    char* ws = (char*)d_ws;
    unsigned short* f_buf = (unsigned short*)(ws);                 // 16.78 MB
    unsigned short* WcT   = (unsigned short*)(ws + 16777216);      // 786 KB
    unsigned short* WoT   = (unsigned short*)(ws + 17563648);      // 131 KB
    unsigned short* WpT   = (unsigned short*)(ws + 17694720);      // 8 KB
    unsigned short* qb    = (unsigned short*)(ws + 17702912);      // 8.39 MB
    unsigned short* kb    = (unsigned short*)(ws + 26091520);      // 8.39 MB
    unsigned short* vT    = (unsigned short*)(ws + 34480128);      // 8.39 MB
    unsigned short* msg   = (unsigned short*)(ws + 42868736);      // 8.39 MB

    prep<<<4096 + 1536, 256, 0, stream>>>(x_source, x_out, g_s, b_s, g_o, b_o,
                                          Wq, Wk, Wv, Wo, Wp, f_buf, WcT, WoT, WpT);
    {
        dim3 g(QKV_ / 128, BN_ / 128);
        qkv_gemm<<<g, 256, 0, stream>>>(f_buf, WcT, qb, kb, vT);
    }
    attn<<<B_ * HEADS_ * (N_ / 64), 256, 0, stream>>>(qb, kb, vT, msg);
    {
        dim3 g(H_ / 64, BN_ / 64);
        out_gemm<<<g, 256, 0, stream>>>(msg, WoT, WpT, x_out, outx, outp);
    }
}

// Round 9
// 191.234 us; speedup vs baseline: 1.0591x; 1.0182x over previous
//
#include <hip/hip_runtime.h>
#include <hip/hip_bf16.h>

#define B_ 16
#define N_ 1024
#define H_ 256
#define HEADS_ 8
#define DH_ 32
#define BN_ (B_*N_)
#define F_ (2*H_)      // 512
#define QKV_ 768

typedef __attribute__((ext_vector_type(8))) __bf16 bf16x8;
typedef __attribute__((ext_vector_type(4))) float floatx4;

// scale(1/sqrt(32)) * log2(e): folded into q so softmax is a bare v_exp (2^x)
#define QSC 0.25506910542339896f

#if __has_builtin(__builtin_amdgcn_exp2f)
#define EXP2(x) __builtin_amdgcn_exp2f(x)
#else
#define EXP2(x) exp2f(x)
#endif

__device__ __forceinline__ unsigned short f2bf(float f) {
    union { float f; unsigned int u; } c; c.f = f;
    unsigned int u = c.u;
    return (unsigned short)((u + 0x7fffu + ((u >> 16) & 1u)) >> 16);
}
__device__ __forceinline__ float bf2f(unsigned short s) {
    union { unsigned int u; float f; } c; c.u = ((unsigned int)s) << 16;
    return c.f;
}
__device__ __forceinline__ unsigned int fbits(float f) {
    union { float f; unsigned int u; } c; c.f = f; return c.u;
}
// pack two floats to bf16x2 via v_perm (round-half-away) — epilogue use
__device__ __forceinline__ unsigned int pk2(float lo, float hi) {
    return __builtin_amdgcn_perm(fbits(hi) + 0x8000u, fbits(lo) + 0x8000u, 0x07060302u);
}
// fast pack for the attn inner loop: hw packed cvt if present, else truncate
// (truncation bias cancels in O = sum(p v)/sum(p) since l uses same p)
__device__ __forceinline__ unsigned int pkp(float lo, float hi) {
#if __has_builtin(__builtin_amdgcn_cvt_pk_bf16_f32)
    typedef __attribute__((ext_vector_type(2))) __bf16 bf2;
    union { bf2 v; unsigned int u; } c;
    c.v = __builtin_amdgcn_cvt_pk_bf16_f32(lo, hi);
    return c.u;
#else
    return __builtin_amdgcn_perm(fbits(hi), fbits(lo), 0x07060302u);
#endif
}

// async global->LDS, 16B per lane; lds dest = wave-uniform base + lane*16
__device__ __forceinline__ void async16(const void* g, void* l) {
    __builtin_amdgcn_global_load_lds(
        (const __attribute__((address_space(1))) unsigned int*)g,
        (__attribute__((address_space(3))) unsigned int*)l,
        16, 0, 0);
}

// ---------------- kernel 1: fused prep = dual LayerNorm + weight pack -----
// blocks [0,4096): LN, 4 rows/block (1 row/wave). blocks [4096,5632): pack.
__global__ __launch_bounds__(256) void prep(
        const float* __restrict__ xs_g, const float* __restrict__ xo_g,
        const float* __restrict__ gs, const float* __restrict__ bs,
        const float* __restrict__ go, const float* __restrict__ bo,
        const float* __restrict__ Wq, const float* __restrict__ Wk,
        const float* __restrict__ Wv, const float* __restrict__ Wo,
        const float* __restrict__ Wp,
        unsigned short* __restrict__ f,
        unsigned short* __restrict__ WcT, unsigned short* __restrict__ WoT,
        unsigned short* __restrict__ WpT) {
    if (blockIdx.x < 4096) {
        int t = threadIdx.x & 63;
        int row = blockIdx.x * 4 + (threadIdx.x >> 6);
        const float4 vs = ((const float4*)(xs_g + (size_t)row * H_))[t];
        const float4 vo = ((const float4*)(xo_g + (size_t)row * H_))[t];
        float s1 = vs.x + vs.y + vs.z + vs.w;
        float s2 = vs.x*vs.x + vs.y*vs.y + vs.z*vs.z + vs.w*vs.w;
        float o1 = vo.x + vo.y + vo.z + vo.w;
        float o2 = vo.x*vo.x + vo.y*vo.y + vo.z*vo.z + vo.w*vo.w;
        #pragma unroll
        for (int m = 1; m < 64; m <<= 1) {
            s1 += __shfl_xor(s1, m); s2 += __shfl_xor(s2, m);
            o1 += __shfl_xor(o1, m); o2 += __shfl_xor(o2, m);
        }
        const float inv = 1.0f / 256.0f;
        float ms = s1 * inv, vvs = s2 * inv - ms * ms;
        float mo = o1 * inv, vvo = o2 * inv - mo * mo;
        float rs = rsqrtf(vvs + 1e-5f);
        float ro = rsqrtf(vvo + 1e-5f);
        float4 g4s = ((const float4*)gs)[t];
        float4 b4s = ((const float4*)bs)[t];
        float4 g4o = ((const float4*)go)[t];
        float4 b4o = ((const float4*)bo)[t];
        ushort4 os, oo;
        os.x = f2bf((vs.x - ms) * rs * g4s.x + b4s.x);
        os.y = f2bf((vs.y - ms) * rs * g4s.y + b4s.y);
        os.z = f2bf((vs.z - ms) * rs * g4s.z + b4s.z);
        os.w = f2bf((vs.w - ms) * rs * g4s.w + b4s.w);
        oo.x = f2bf((vo.x - mo) * ro * g4o.x + b4o.x);
        oo.y = f2bf((vo.y - mo) * ro * g4o.y + b4o.y);
        oo.z = f2bf((vo.z - mo) * ro * g4o.z + b4o.z);
        oo.w = f2bf((vo.w - mo) * ro * g4o.w + b4o.w);
        *(ushort4*)(f + (size_t)row * F_ + 4 * t) = os;
        *(ushort4*)(f + (size_t)row * F_ + H_ + 4 * t) = oo;
    } else {
        int i = (blockIdx.x - 4096) * 256 + threadIdx.x;
        const int total1 = QKV_ * F_;   // WcT[n][k]
        if (i < total1) {
            int n = i / F_, k = i % F_;
            float w;
            if (n < 256)      w = Wq[(size_t)k * H_ + n];
            else if (n < 512) w = Wk[(size_t)k * H_ + (n - 256)];
            else              w = Wv[(size_t)k * H_ + (n - 512)];
            WcT[i] = f2bf(w);
        }
        const int total2 = H_ * H_;     // WoT[n][k]
        if (i < total2) {
            int n = i / H_, k = i % H_;
            WoT[i] = f2bf(Wo[(size_t)k * H_ + n]);
        }
        if (i < 16 * H_) {              // WpT[n][k] = (Wo @ Wp)^T bf16, n<3
            int n = i >> 8, k = i & 255;
            if (n < 3) {
                float s = 0.f;
                for (int m = 0; m < H_; ++m) s += Wo[(size_t)k * H_ + m] * Wp[m * 3 + n];
                WpT[i] = f2bf(s);
            } else {
                WpT[i] = 0;
            }
        }
    }
}

// ---------------- kernel 2: QKV GEMM (128x128 LDS tile) -------------------
// q prescaled by QSC. Epilogue bounces C through LDS so all global stores
// are coalesced uint4 runs (q/k: along d, 64B segs; v: along tok, 256B runs).
__global__ __launch_bounds__(256) void qkv_gemm(
        const unsigned short* __restrict__ f,
        const unsigned short* __restrict__ WcT,
        unsigned short* __restrict__ qb,
        unsigned short* __restrict__ kb,
        unsigned short* __restrict__ vT) {
    __shared__ __align__(16) unsigned short As[128 * 32];
    __shared__ __align__(16) unsigned short Bs[128 * 32];
    __shared__ __align__(16) unsigned short Cs[128 * 136];  // padded bounce
    int t = threadIdx.x;
    int w = t >> 6, lane = t & 63;
    int r = lane & 15, qd = lane >> 4;
    int wm = (w >> 1) * 64, wn = (w & 1) * 64;
    int m0 = blockIdx.y * 128, n0 = blockIdx.x * 128;
    int lrow = lane >> 2, lcol = (lane & 3) * 8;
    floatx4 acc[4][4] = {};
    const unsigned short* gA = f   + (size_t)(m0 + w * 32 + lrow) * F_ + lcol;
    const unsigned short* gB = WcT + (size_t)(n0 + w * 32 + lrow) * F_ + lcol;
    unsigned short* lA = As + (w * 32) * 32;
    unsigned short* lB = Bs + (w * 32) * 32;
    for (int k0 = 0; k0 < F_; k0 += 32) {
        async16(gA + k0,            lA);
        async16(gA + k0 + 16 * F_,  lA + 16 * 32);
        async16(gB + k0,            lB);
        async16(gB + k0 + 16 * F_,  lB + 16 * 32);
        __syncthreads();
        bf16x8 aF[4], bF[4];
        #pragma unroll
        for (int mt = 0; mt < 4; ++mt)
            aF[mt] = *(const bf16x8*)(As + (wm + mt * 16 + r) * 32 + qd * 8);
        #pragma unroll
        for (int nt = 0; nt < 4; ++nt)
            bF[nt] = *(const bf16x8*)(Bs + (wn + nt * 16 + r) * 32 + qd * 8);
        #pragma unroll
        for (int mt = 0; mt < 4; ++mt)
            #pragma unroll
            for (int nt = 0; nt < 4; ++nt)
                acc[mt][nt] = __builtin_amdgcn_mfma_f32_16x16x32_bf16(aF[mt], bF[nt], acc[mt][nt], 0, 0, 0);
        __syncthreads();
    }
    int sec = n0 >> 8;                  // block-uniform: 0=q 1=k 2=v
    int b = m0 >> 10, tlb = m0 & 1023;  // batch + token base (m0 mult of 128)
    int base_h = (n0 >> 5) & 7;         // 0 or 4
    if (sec < 2) {
        // Cs[tok][col], q scaled at write
        #pragma unroll
        for (int nt = 0; nt < 4; ++nt) {
            int c = wn + nt * 16 + r;
            #pragma unroll
            for (int mt = 0; mt < 4; ++mt) {
                int row0 = wm + mt * 16 + qd * 4;
                #pragma unroll
                for (int i = 0; i < 4; ++i) {
                    float v = acc[mt][nt][i];
                    if (sec == 0) v *= QSC;
                    Cs[(row0 + i) * 136 + c] = f2bf(v);
                }
            }
        }
        __syncthreads();
        int d0 = (t & 3) * 8;
        int h4 = (t >> 2) & 3;
        int c_l = h4 * 32 + d0;
        int h = base_h + h4;
        unsigned short* dst0 = (sec == 0 ? qb : kb)
            + ((size_t)(b * 8 + h) * 1024 + tlb) * 32 + d0;
        int tok_l0 = t >> 4;
        #pragma unroll
        for (int p = 0; p < 8; ++p) {
            int tok_l = p * 16 + tok_l0;
            uint4 vv = *(const uint4*)&Cs[tok_l * 136 + c_l];
            *(uint4*)(dst0 + (size_t)tok_l * 32) = vv;
        }
    } else {
        // Cs[col][tok] (transposed), packed pair writes
        #pragma unroll
        for (int nt = 0; nt < 4; ++nt) {
            int c = wn + nt * 16 + r;
            #pragma unroll
            for (int mt = 0; mt < 4; ++mt) {
                int tok0 = wm + mt * 16 + qd * 4;
                uint2 pk;
                pk.x = pk2(acc[mt][nt][0], acc[mt][nt][1]);
                pk.y = pk2(acc[mt][nt][2], acc[mt][nt][3]);
                *(uint2*)&Cs[c * 136 + tok0] = pk;
            }
        }
        __syncthreads();
        int c_l = t >> 1, half = t & 1;
        int h = base_h + (c_l >> 5), d = c_l & 31;
        unsigned short* dst = vT + ((size_t)(b * 8 + h) * 32 + d) * 1024
                              + tlb + half * 64;
        #pragma unroll
        for (int j = 0; j < 8; ++j) {
            uint4 vv = *(const uint4*)&Cs[c_l * 136 + half * 64 + j * 8];
            *(uint4*)(dst + j * 8) = vv;
        }
    }
}

// ---------------- kernel 3: flash attention, split-K across waves ---------
// Block = 64 q-rows x one (b,h). Wave w handles keys [w*256,(w+1)*256) for
// ALL 64 q-rows. fp32 partials through LDS (measured best, R5). Fixed-max
// softmax, l via ones-MFMA, fast bf16 pack in the hot loop.
__global__ __launch_bounds__(256) void attn(
        const unsigned short* __restrict__ qb,
        const unsigned short* __restrict__ kb,
        const unsigned short* __restrict__ vT,
        unsigned short* __restrict__ msg) {
    __shared__ float ob[4][32][66];     // [wave][d][q] transposed partials
    __shared__ float lb[4][64];         // [wave][q] row-sum partials
    int blk = blockIdx.x;
    int qt = blk & 15;
    int h  = (blk >> 4) & 7;
    int b  = blk >> 7;
    int t = threadIdx.x;
    int w = t >> 6, lane = t & 63;
    int r = lane & 15, qd = lane >> 4;
    int q0 = qt * 64;
    size_t hb = (size_t)b * 8 + h;
    const unsigned short* qs = qb + hb * (1024 * 32);
    const unsigned short* ks = kb + hb * (1024 * 32);
    const unsigned short* vs = vT + hb * (32 * 1024);
    bf16x8 qf[4];
    #pragma unroll
    for (int i = 0; i < 4; ++i)
        qf[i] = *(const bf16x8*)(qs + (size_t)(q0 + i * 16 + r) * 32 + qd * 8);
    union { unsigned int u[4]; bf16x8 v; } onesu;
    onesu.u[0] = onesu.u[1] = onesu.u[2] = onesu.u[3] = 0x3F803F80u;
    const bf16x8 onesv = onesu.v;
    floatx4 o0[4] = {}, o1[4] = {}, ol[4] = {};
    int srcA = ((qd & 1) * 2) * 16 + r;
    int srcB = srcA + 16;
    bool hiq = qd >= 2;
    int kb0 = w * 256;
    for (int kc = 0; kc < 256; kc += 32) {
        int kk = kb0 + kc;
        bf16x8 kf0 = *(const bf16x8*)(ks + (size_t)(kk + r) * 32 + qd * 8);
        bf16x8 kf1 = *(const bf16x8*)(ks + (size_t)(kk + 16 + r) * 32 + qd * 8);
        bf16x8 vf0 = *(const bf16x8*)(vs + (size_t)r * 1024 + kk + qd * 8);
        bf16x8 vf1 = *(const bf16x8*)(vs + (size_t)(16 + r) * 1024 + kk + qd * 8);
        #pragma unroll
        for (int i = 0; i < 4; ++i) {
            floatx4 z = {0.f,0.f,0.f,0.f};
            floatx4 s0 = __builtin_amdgcn_mfma_f32_16x16x32_bf16(kf0, qf[i], z, 0, 0, 0);
            floatx4 s1 = __builtin_amdgcn_mfma_f32_16x16x32_bf16(kf1, qf[i], z, 0, 0, 0);
            float e0[4], e1[4];
            #pragma unroll
            for (int j = 0; j < 4; ++j) {
                e0[j] = EXP2(s0[j]);
                e1[j] = EXP2(s1[j]);
            }
            unsigned int t00 = pkp(e0[0], e0[1]), t01 = pkp(e0[2], e0[3]);
            unsigned int t10 = pkp(e1[0], e1[1]), t11 = pkp(e1[2], e1[3]);
            unsigned int a0 = __shfl((int)t00, srcA), a1 = __shfl((int)t01, srcA);
            unsigned int b0 = __shfl((int)t00, srcB), b1 = __shfl((int)t01, srcB);
            unsigned int c0 = __shfl((int)t10, srcA), c1 = __shfl((int)t11, srcA);
            unsigned int d0 = __shfl((int)t10, srcB), d1 = __shfl((int)t11, srcB);
            union { unsigned int u[4]; bf16x8 v; } pf;
            pf.u[0] = hiq ? c0 : a0;
            pf.u[1] = hiq ? c1 : a1;
            pf.u[2] = hiq ? d0 : b0;
            pf.u[3] = hiq ? d1 : b1;
            o0[i] = __builtin_amdgcn_mfma_f32_16x16x32_bf16(vf0, pf.v, o0[i], 0, 0, 0);
            o1[i] = __builtin_amdgcn_mfma_f32_16x16x32_bf16(vf1, pf.v, o1[i], 0, 0, 0);
            ol[i] = __builtin_amdgcn_mfma_f32_16x16x32_bf16(onesv, pf.v, ol[i], 0, 0, 0);
        }
    }
    #pragma unroll
    for (int i = 0; i < 4; ++i) {
        #pragma unroll
        for (int j = 0; j < 4; ++j) {
            ob[w][qd * 4 + j][i * 16 + r]      = o0[i][j];
            ob[w][16 + qd * 4 + j][i * 16 + r] = o1[i][j];
        }
        if (qd == 0) lb[w][i * 16 + r] = ol[i][0];
    }
    __syncthreads();
    {
        int q2 = t >> 2, dg = t & 3;
        float acc8[8] = {0.f,0.f,0.f,0.f,0.f,0.f,0.f,0.f};
        float L = 0.f;
        #pragma unroll
        for (int ww = 0; ww < 4; ++ww) {
            L += lb[ww][q2];
            #pragma unroll
            for (int j = 0; j < 8; ++j)
                acc8[j] += ob[ww][dg * 8 + j][q2];
        }
        float rinv = 1.0f / L;
        uint4 pkd;
        pkd.x = pk2(acc8[0] * rinv, acc8[1] * rinv);
        pkd.y = pk2(acc8[2] * rinv, acc8[3] * rinv);
        pkd.z = pk2(acc8[4] * rinv, acc8[5] * rinv);
        pkd.w = pk2(acc8[6] * rinv, acc8[7] * rinv);
        *(uint4*)(msg + ((size_t)(b * N_ + q0 + q2)) * H_ + h * DH_ + dg * 8) = pkd;
    }
}

// ---------------- kernel 4: Wo GEMM + residual + fused p head -------------
// grid (H_/64, BN_/64). Waves with wn==0 also accumulate p = msg @ WpT^T
// (WpT rows >=3 are zero) and store p for their token rows.
__global__ __launch_bounds__(256) void out_gemm(
        const unsigned short* __restrict__ msg,
        const unsigned short* __restrict__ WoT,
        const unsigned short* __restrict__ WpT,
        const float* __restrict__ x_out,
        float* __restrict__ outx, float* __restrict__ outp) {
    __shared__ __align__(16) unsigned short As[64 * 32];
    __shared__ __align__(16) unsigned short Bs[64 * 32];
    int t = threadIdx.x;
    int w = t >> 6, lane = t & 63;
    int r = lane & 15, qd = lane >> 4;
    int wm = (w >> 1) * 32, wn = (w & 1) * 32;
    int m0 = blockIdx.y * 64, n0 = blockIdx.x * 64;
    int lrow = lane >> 2, lcol = (lane & 3) * 8;
    bool do_p = (blockIdx.x == 0) && ((w & 1) == 0);
    floatx4 acc[2][2] = {};
    floatx4 accp[2] = {};
    const unsigned short* gA = msg + (size_t)(m0 + w * 16 + lrow) * H_ + lcol;
    const unsigned short* gB = WoT + (size_t)(n0 + w * 16 + lrow) * H_ + lcol;
    unsigned short* lA = As + (w * 16) * 32;
    unsigned short* lB = Bs + (w * 16) * 32;
    for (int k0 = 0; k0 < H_; k0 += 32) {
        async16(gA + k0, lA);
        async16(gB + k0, lB);
        __syncthreads();
        bf16x8 aF[2], bF[2];
        #pragma unroll
        for (int mt = 0; mt < 2; ++mt)
            aF[mt] = *(const bf16x8*)(As + (wm + mt * 16 + r) * 32 + qd * 8);
        #pragma unroll
        for (int nt = 0; nt < 2; ++nt)
            bF[nt] = *(const bf16x8*)(Bs + (wn + nt * 16 + r) * 32 + qd * 8);
        #pragma unroll
        for (int mt = 0; mt < 2; ++mt)
            #pragma unroll
            for (int nt = 0; nt < 2; ++nt)
                acc[mt][nt] = __builtin_amdgcn_mfma_f32_16x16x32_bf16(aF[mt], bF[nt], acc[mt][nt], 0, 0, 0);
        if (do_p) {
            bf16x8 bP = *(const bf16x8*)(WpT + (size_t)r * H_ + k0 + qd * 8);
            #pragma unroll
            for (int mt = 0; mt < 2; ++mt)
                accp[mt] = __builtin_amdgcn_mfma_f32_16x16x32_bf16(aF[mt], bP, accp[mt], 0, 0, 0);
        }
        __syncthreads();
    }
    #pragma unroll
    for (int nt = 0; nt < 2; ++nt) {
        int cg = n0 + wn + nt * 16 + r;
        #pragma unroll
        for (int mt = 0; mt < 2; ++mt) {
            int tok = m0 + wm + mt * 16 + qd * 4;
            #pragma unroll
            for (int i = 0; i < 4; ++i) {
                size_t idx = (size_t)(tok + i) * H_ + cg;
                outx[idx] = x_out[idx] + acc[mt][nt][i];
            }
        }
    }
    if (do_p && r < 3) {
        #pragma unroll
        for (int mt = 0; mt < 2; ++mt) {
            int tok = m0 + wm + mt * 16 + qd * 4;
            #pragma unroll
            for (int i = 0; i < 4; ++i)
                outp[(size_t)(tok + i) * 3 + r] = accp[mt][i];
        }
    }
}

extern "C" void kernel_launch(void* const* d_in, const int* in_sizes, int n_in,
                              void* d_out, int out_size, void* d_ws, size_t ws_size,
                              hipStream_t stream) {
    const float* x_source = (const float*)d_in[0];
    const float* x_out = (const float*)d_in[2];
    const float* g_s = (const float*)d_in[4];
    const float* b_s = (const float*)d_in[5];
    const float* g_o = (const float*)d_in[6];
    const float* b_o = (const float*)d_in[7];
    const float* Wq = (const float*)d_in[8];
    const float* Wk = (const float*)d_in[9];
    const float* Wv = (const float*)d_in[10];
    const float* Wo = (const float*)d_in[11];
    const float* Wp = (const float*)d_in[12];

    float* outx = (float*)d_out;                  // [BN][256]
    float* outp = outx + (size_t)BN_ * H_;        // [BN][3]

    char* ws = (char*)d_ws;
    unsigned short* f_buf = (unsigned short*)(ws);                 // 16.78 MB
    unsigned short* WcT   = (unsigned short*)(ws + 16777216);      // 786 KB
    unsigned short* WoT   = (unsigned short*)(ws + 17563648);      // 131 KB
    unsigned short* WpT   = (unsigned short*)(ws + 17694720);      // 8 KB
    unsigned short* qb    = (unsigned short*)(ws + 17702912);      // 8.39 MB
    unsigned short* kb    = (unsigned short*)(ws + 26091520);      // 8.39 MB
    unsigned short* vT    = (unsigned short*)(ws + 34480128);      // 8.39 MB
    unsigned short* msg   = (unsigned short*)(ws + 42868736);      // 8.39 MB

    prep<<<4096 + 1536, 256, 0, stream>>>(x_source, x_out, g_s, b_s, g_o, b_o,
                                          Wq, Wk, Wv, Wo, Wp, f_buf, WcT, WoT, WpT);
    {
        dim3 g(QKV_ / 128, BN_ / 128);
        qkv_gemm<<<g, 256, 0, stream>>>(f_buf, WcT, qb, kb, vT);
    }
    attn<<<B_ * HEADS_ * (N_ / 64), 256, 0, stream>>>(qb, kb, vT, msg);
    {
        dim3 g(H_ / 64, BN_ / 64);
        out_gemm<<<g, 256, 0, stream>>>(msg, WoT, WpT, x_out, outx, outp);
    }
}